// Round 7
// baseline (246.887 us; speedup 1.0000x reference)
//
#include <hip/hip_runtime.h>
#include <math.h>

// Problem constants: B=8, C=64 (in), OC=64 (out), H=W=128, K=3x3=9, PAD=1.
#define Hn 128
#define Wn 128
#define HW 16384
#define NPIX 131072
#define EPSv 1e-5f

// ws layout (floats)
#define XT_OFF   0            // x_t bf16 channels-last [b][y][x][c]: 8388608 shorts = 4194304 floats
#define WBTA_OFF 4194304      // 20480 shorts = 10240 floats
#define WBTB_OFF 4204544      // 40960 shorts = 20480 floats
#define STAT_OFF 4225024      // 128 (sum[64], sumsq[64])

// R17 (this round): (1) asm-pinned 16-deep gather burst in phase 3. R13/R14/
// R15 proved the allocator collapses any C-level load window to ~4 in flight
// (VGPR 32/36/60). asm volatile global_load_dwordx4 x16 with immediate
// offsets is un-collapsible: order pinned, 16 quads forced live. Consume
// after s_waitcnt vmcnt(0) + sched_barrier(0) (rule-18 fence). (2) stats
// fused into the epilogue (acc already in registers; shfl over k-slice lanes
// -> LDS cross-wave -> atomicAdd) -> stats2 dispatch + 33.5 MB pass deleted.

typedef short s16x8 __attribute__((ext_vector_type(8)));
typedef unsigned short u16x4 __attribute__((ext_vector_type(4)));
typedef float f32x4 __attribute__((ext_vector_type(4)));
typedef unsigned int u32x4 __attribute__((ext_vector_type(4)));

__device__ __forceinline__ unsigned short f2bf(float f) {
  unsigned u = __float_as_uint(f);
  return (unsigned short)((u + 0x7fffu + ((u >> 16) & 1u)) >> 16);  // RNE
}
__device__ __forceinline__ float bf2f(unsigned short s) {
  return __uint_as_float((unsigned)s << 16);
}
__device__ __forceinline__ unsigned cvt_pk_bf16(float lo, float hi) {
  unsigned r;
  asm("v_cvt_pk_bf16_f32 %0, %1, %2" : "=v"(r) : "v"(lo), "v"(hi));
  return r;
}

// pinned 16B global load with immediate byte offset (order preserved among volatile asm)
#define GLD(dst, ptr, off) \
  asm volatile("global_load_dwordx4 %0, %1, off offset:" #off : "=&v"(dst) : "v"(ptr))

// ---------------- prep: pack weights into MFMA operand order; zero stat ----------------
__global__ __launch_bounds__(256) void prep_kernel(
    const float* __restrict__ off_w, const float* __restrict__ mod_w,
    const float* __restrict__ w, unsigned short* __restrict__ wbtA,
    unsigned short* __restrict__ wbtB, float* __restrict__ stat) {
  int i = blockIdx.x * 256 + threadIdx.x;
  if (i < 128) stat[i] = 0.f;
  if (i < 20480) {
    // wbtA: A-operand (weights as rows) for phase 1 of the fused kernel.
    int e = i & 31, oc = (i >> 5) & 31, it = i >> 10;
    int tp = it % 5, chunk = it / 5;
    int tap = tp * 2 + (e >> 4);
    int c = (chunk << 4) + (e & 15);
    float v = 0.f;
    if (tap < 9) {
      if (oc < 18) v = off_w[(oc * 64 + c) * 9 + tap];
      else if (oc < 27) v = mod_w[((oc - 18) * 64 + c) * 9 + tap];
    }
    wbtA[i] = f2bf(v);
  } else if (i < 20480 + 40960) {
    // wbtB: B-operand fragments for phase 3 (deform).
    // index = ((it*4 + nt)*64 + lane)*8 + j
    // value = w[oc = nt*16 + (lane&15)][c][tap], where
    //   tap = (it%5)*2 + (lane>>5), c = (it/5)*16 + ((lane>>4)&1)*8 + j
    int j = i - 20480;
    int j3 = j & 7;
    int l = (j >> 3) & 63;
    int nt = (j >> 9) & 3;
    int it = j >> 11;
    int tp = it % 5, chunk = it / 5;
    int tap = tp * 2 + (l >> 5);
    int c = (chunk << 4) + (((l >> 4) & 1) << 3) + j3;
    int oc = (nt << 4) + (l & 15);
    float v = (tap < 9) ? w[(oc * 64 + c) * 9 + tap] : 0.f;
    wbtB[j] = f2bf(v);
  }
}

// ---------------- xform: x (NCHW fp32) -> x_t (NHWC bf16) ----------------
__global__ __launch_bounds__(256) void xform_kernel(
    const float* __restrict__ x, unsigned short* __restrict__ xt) {
  int blk = blockIdx.x;                       // 512 blocks
  int b = blk & 7;
  int hw = ((blk >> 3) << 8) + threadIdx.x;   // 0..16383
  const float* xb = x + ((size_t)(b << 6) << 14) + hw;
  unsigned short* o = xt + (((size_t)(b << 14)) + hw) * 64;
#pragma unroll
  for (int g = 0; g < 8; ++g) {
    float v[8];
#pragma unroll
    for (int j = 0; j < 8; ++j) v[j] = xb[(size_t)((g << 3) + j) << 14];
    s16x8 pk;
#pragma unroll
    for (int j = 0; j < 8; ++j) pk[j] = (short)f2bf(v[j]);
    *(s16x8*)(o + (g << 3)) = pk;
  }
}

// ---------------- fused kernel: convA (->LDS) + geometry + deform MFMA + stats ----------------
__global__ __launch_bounds__(256, 4) void fused_dconv_kernel(
    const unsigned short* __restrict__ xt, const unsigned short* __restrict__ wbtA,
    const unsigned short* __restrict__ wbtB,
    const float* __restrict__ off_b, const float* __restrict__ mod_b,
    const float* __restrict__ bias, float* __restrict__ y,
    float* __restrict__ stat) {
  __shared__ float offm[27 * 128];              // 13824 B: off rows 0..17, mask rows 18..26; reused for stats
  __shared__ unsigned short geow[9 * 128 * 4];  // 9216 B: w00,w01,w10,w11 bf16 (mask folded)
  __shared__ unsigned short geoi[9 * 128];      // 2304 B: ibase = rbase*128+cbase
  int t = threadIdx.x;
  int bx = blockIdx.x;                  // 1024 = 8 b x 128 h
  int b = bx & 7, h = bx >> 3;
  int lane = t & 63, wv = t >> 6;
  int ln = lane & 15, quad = (lane >> 4) & 3;
  int hw = h << 7;

  const unsigned short* xtb = xt + ((size_t)(b << 14)) * 64;

  // ===== phase 1: offset+mask conv via MFMA, results to LDS =====
  {
    int p0 = (wv << 5) + ln, p1 = p0 + 16;
    int s_ = quad >> 1, cj = (quad & 1) << 3;
    f32x4 acc1[2][2];
#pragma unroll
    for (int mt = 0; mt < 2; ++mt)
#pragma unroll
      for (int nt = 0; nt < 2; ++nt) acc1[mt][nt] = (f32x4){0.f, 0.f, 0.f, 0.f};

#pragma unroll 5
    for (int it = 0; it < 20; ++it) {
      int chunk = it / 5, tp = it - chunk * 5;
      int tap = tp * 2 + s_;
      s16x8 B0 = (s16x8){0, 0, 0, 0, 0, 0, 0, 0};
      s16x8 B1 = (s16x8){0, 0, 0, 0, 0, 0, 0, 0};
      if (tap < 9) {
        int gy = h + tap / 3 - 1;
        if (gy >= 0 && gy < Hn) {
          const unsigned short* rowp = xtb + ((size_t)(gy << 7)) * 64 + (chunk << 4) + cj;
          int gx0 = p0 + tap % 3 - 1;
          int gx1 = p1 + tap % 3 - 1;
          if (gx0 >= 0 && gx0 < Wn) B0 = *(const s16x8*)(rowp + (gx0 << 6));
          if (gx1 >= 0 && gx1 < Wn) B1 = *(const s16x8*)(rowp + (gx1 << 6));
        }
      }
#pragma unroll
      for (int mt = 0; mt < 2; ++mt) {
        s16x8 A = *(const s16x8*)(wbtA + (size_t)((it << 5) + (mt << 4) + ln) * 32 + (quad << 3));
        acc1[mt][0] = __builtin_amdgcn_mfma_f32_16x16x32_bf16(A, B0, acc1[mt][0], 0, 0, 0);
        acc1[mt][1] = __builtin_amdgcn_mfma_f32_16x16x32_bf16(A, B1, acc1[mt][1], 0, 0, 0);
      }
    }

#pragma unroll
    for (int mt = 0; mt < 2; ++mt)
#pragma unroll
      for (int r = 0; r < 4; ++r) {
        int oc = (mt << 4) + (quad << 2) + r;
#pragma unroll
        for (int nt = 0; nt < 2; ++nt) {
          int px = (wv << 5) + (nt << 4) + ln;
          float val = acc1[mt][nt][r];
          if (oc < 18) {
            offm[(oc << 7) + px] = val + off_b[oc];
          } else if (oc < 27) {
            float z = val + mod_b[oc - 18];
            offm[(oc << 7) + px] = 2.f / (1.f + expf(-z));
          }
        }
      }
  }
  __syncthreads();

  // ===== phase 2: geometry for 128 px x 9 taps from LDS =====
  for (int i = t; i < 1152; i += 256) {
    int tap = i >> 7, p2 = i & 127;
    float dy = offm[((2 * tap) << 7) + p2];
    float dx = offm[((2 * tap + 1) << 7) + p2];
    float m = offm[((18 + tap) << 7) + p2];
    float py = dy + (float)(h + tap / 3 - 1);
    float pxf = dx + (float)(p2 + tap % 3 - 1);
    float y0f = floorf(py), x0f = floorf(pxf);
    float ly = py - y0f, lx = pxf - x0f;
    int y0 = (int)y0f, x0 = (int)x0f;
    int y1 = y0 + 1, x1 = x0 + 1;
    float fy0 = (y0 >= 0 && y0 < Hn) ? 1.f : 0.f;
    float fy1 = (y1 >= 0 && y1 < Hn) ? 1.f : 0.f;
    float fx0 = (x0 >= 0 && x0 < Wn) ? 1.f : 0.f;
    float fx1 = (x1 >= 0 && x1 < Wn) ? 1.f : 0.f;
    float ax0 = (1.f - lx) * fx0, ax1 = lx * fx1;
    float ay0 = (1.f - ly) * fy0 * m, ay1 = ly * fy1 * m;
    int cy0 = min(max(y0, 0), Hn - 1), cy1 = min(max(y1, 0), Hn - 1);
    int cx0 = min(max(x0, 0), Wn - 1), cx1 = min(max(x1, 0), Wn - 1);
    int cbase = min(cx0, Wn - 2), rbase = min(cy0, Hn - 2);
    float gx0 = (cx0 == cbase ? ax0 : 0.f) + (cx1 == cbase ? ax1 : 0.f);
    float gx1 = (cx0 == cbase + 1 ? ax0 : 0.f) + (cx1 == cbase + 1 ? ax1 : 0.f);
    float gy0 = (cy0 == rbase ? ay0 : 0.f) + (cy1 == rbase ? ay1 : 0.f);
    float gy1 = (cy0 == rbase + 1 ? ay0 : 0.f) + (cy1 == rbase + 1 ? ay1 : 0.f);
    unsigned short* gw = geow + i * 4;
    gw[0] = f2bf(gy0 * gx0);
    gw[1] = f2bf(gy0 * gx1);
    gw[2] = f2bf(gy1 * gx0);
    gw[3] = f2bf(gy1 * gx1);
    geoi[i] = (unsigned short)((rbase << 7) + cbase);
  }
  __syncthreads();

  // ===== phase 3: deform MFMA with pinned 16-deep gather bursts =====
  int l4 = ln;
  int s4 = lane >> 4;        // k-slice 0..3
  int tapS = lane >> 5;      // which tap of the pair
  int chalf = s4 & 1;        // which 8ch half of the 16ch chunk

  f32x4 acc[2][4];  // [m-tile (px 16)][n-tile (oc 16)]
#pragma unroll
  for (int m = 0; m < 2; ++m)
#pragma unroll
    for (int n = 0; n < 4; ++n) acc[m][n] = (f32x4){0.f, 0.f, 0.f, 0.f};

#pragma unroll
  for (int m = 0; m < 2; ++m) {
#pragma unroll 1
    for (int tp = 0; tp < 5; ++tp) {
      int tap = tp * 2 + tapS;
      bool live = (tap < 9);
      int px = (wv << 5) + (m << 4) + l4;
      int gidx = ((live ? tap : 0) << 7) + px;
      u16x4 wq = *(const u16x4*)(geow + gidx * 4);
      unsigned ib = geoi[gidx];
      float w00 = live ? bf2f(wq[0]) : 0.f;
      float w01 = live ? bf2f(wq[1]) : 0.f;
      float w10 = live ? bf2f(wq[2]) : 0.f;
      float w11 = live ? bf2f(wq[3]) : 0.f;
      const unsigned short* base0 = xtb + (size_t)ib * 64 + (chalf << 3);  // row y0
      const unsigned short* base1 = base0 + 8192;                          // row y1
      // 16 pinned loads: 4 chunks x 4 corners. offsets: chunk*32B, +128B for x+1.
      u32x4 cA0, cA1, cA2, cA3, cB0, cB1, cB2, cB3;
      u32x4 cC0, cC1, cC2, cC3, cD0, cD1, cD2, cD3;
      GLD(cA0, base0, 0);   GLD(cA1, base0, 32);  GLD(cA2, base0, 64);  GLD(cA3, base0, 96);
      GLD(cB0, base0, 128); GLD(cB1, base0, 160); GLD(cB2, base0, 192); GLD(cB3, base0, 224);
      GLD(cC0, base1, 0);   GLD(cC1, base1, 32);  GLD(cC2, base1, 64);  GLD(cC3, base1, 96);
      GLD(cD0, base1, 128); GLD(cD1, base1, 160); GLD(cD2, base1, 192); GLD(cD3, base1, 224);
      asm volatile("s_waitcnt vmcnt(0)" ::: "memory");
      __builtin_amdgcn_sched_barrier(0);
      s16x8 c00[4] = {__builtin_bit_cast(s16x8, cA0), __builtin_bit_cast(s16x8, cA1),
                      __builtin_bit_cast(s16x8, cA2), __builtin_bit_cast(s16x8, cA3)};
      s16x8 c01[4] = {__builtin_bit_cast(s16x8, cB0), __builtin_bit_cast(s16x8, cB1),
                      __builtin_bit_cast(s16x8, cB2), __builtin_bit_cast(s16x8, cB3)};
      s16x8 c10[4] = {__builtin_bit_cast(s16x8, cC0), __builtin_bit_cast(s16x8, cC1),
                      __builtin_bit_cast(s16x8, cC2), __builtin_bit_cast(s16x8, cC3)};
      s16x8 c11[4] = {__builtin_bit_cast(s16x8, cD0), __builtin_bit_cast(s16x8, cD1),
                      __builtin_bit_cast(s16x8, cD2), __builtin_bit_cast(s16x8, cD3)};
#pragma unroll
      for (int chunk = 0; chunk < 4; ++chunk) {
        int it = chunk * 5 + tp;
        u32x4 au;
#pragma unroll
        for (int jj = 0; jj < 4; ++jj) {
          float v0 = w00 * bf2f((unsigned short)c00[chunk][2 * jj]) +
                     w01 * bf2f((unsigned short)c01[chunk][2 * jj]) +
                     w10 * bf2f((unsigned short)c10[chunk][2 * jj]) +
                     w11 * bf2f((unsigned short)c11[chunk][2 * jj]);
          float v1 = w00 * bf2f((unsigned short)c00[chunk][2 * jj + 1]) +
                     w01 * bf2f((unsigned short)c01[chunk][2 * jj + 1]) +
                     w10 * bf2f((unsigned short)c10[chunk][2 * jj + 1]) +
                     w11 * bf2f((unsigned short)c11[chunk][2 * jj + 1]);
          au[jj] = cvt_pk_bf16(v0, v1);
        }
        s16x8 A = __builtin_bit_cast(s16x8, au);
        const unsigned short* wb = wbtB + (((size_t)it) << 11) + (lane << 3);
#pragma unroll
        for (int n = 0; n < 4; ++n) {
          s16x8 Bf = *(const s16x8*)(wb + (n << 9));
          acc[m][n] = __builtin_amdgcn_mfma_f32_16x16x32_bf16(A, Bf, acc[m][n], 0, 0, 0);
        }
      }
    }
  }

  // ===== epilogue: bias + store + per-channel stats (fused) =====
  float sac[4], ssc[4];
#pragma unroll
  for (int n = 0; n < 4; ++n) { sac[n] = 0.f; ssc[n] = 0.f; }
#pragma unroll
  for (int m = 0; m < 2; ++m) {
    int px0 = (wv << 5) + (m << 4) + (s4 << 2);
#pragma unroll
    for (int n = 0; n < 4; ++n) {
      int oc = (n << 4) + l4;
      float bv = bias[oc];
      float4 o;
      o.x = acc[m][n][0] + bv;
      o.y = acc[m][n][1] + bv;
      o.z = acc[m][n][2] + bv;
      o.w = acc[m][n][3] + bv;
      sac[n] += o.x + o.y + o.z + o.w;
      ssc[n] += o.x * o.x + o.y * o.y + o.z * o.z + o.w * o.w;
      *(float4*)(y + (((size_t)(b << 6) + oc) << 14) + hw + px0) = o;
    }
  }
  // reduce over the 4 k-slice lanes (same l4, different s4): xor 16, 32
#pragma unroll
  for (int n = 0; n < 4; ++n) {
    sac[n] += __shfl_xor(sac[n], 16);
    sac[n] += __shfl_xor(sac[n], 32);
    ssc[n] += __shfl_xor(ssc[n], 16);
    ssc[n] += __shfl_xor(ssc[n], 32);
  }
  if (lane < 16) {
#pragma unroll
    for (int n = 0; n < 4; ++n) {
      int oc = (n << 4) + lane;
      offm[(wv << 6) + oc] = sac[n];
      offm[256 + (wv << 6) + oc] = ssc[n];
    }
  }
  __syncthreads();
  if (t < 64) {
    float S = offm[t] + offm[64 + t] + offm[128 + t] + offm[192 + t];
    float SS = offm[256 + t] + offm[320 + t] + offm[384 + t] + offm[448 + t];
    atomicAdd(stat + t, S);
    atomicAdd(stat + 64 + t, SS);
  }
}

// ---------------- kernel D: batchnorm scale/shift + relu, in place ----------------
__global__ __launch_bounds__(256) void bnrelu_kernel(
    float* __restrict__ y, const float* __restrict__ stat,
    const float* __restrict__ gamma, const float* __restrict__ beta) {
  float4* y4 = (float4*)y;
  for (int i = blockIdx.x * 256 + threadIdx.x; i < 2097152; i += gridDim.x * 256) {
    int c = (i >> 12) & 63;
    float mean = stat[c] * (1.f / (float)NPIX);
    float var = stat[64 + c] * (1.f / (float)NPIX) - mean * mean;
    float r = rsqrtf(var + EPSv);
    float g = gamma[c] * r;
    float bt = beta[c] - mean * g;
    float4 v = y4[i];
    v.x = fmaxf(v.x * g + bt, 0.f);
    v.y = fmaxf(v.y * g + bt, 0.f);
    v.z = fmaxf(v.z * g + bt, 0.f);
    v.w = fmaxf(v.w * g + bt, 0.f);
    y4[i] = v;
  }
}

extern "C" void kernel_launch(void* const* d_in, const int* in_sizes, int n_in,
                              void* d_out, int out_size, void* d_ws, size_t ws_size,
                              hipStream_t stream) {
  const float* x     = (const float*)d_in[0];
  const float* off_w = (const float*)d_in[1];
  const float* off_b = (const float*)d_in[2];
  const float* mod_w = (const float*)d_in[3];
  const float* mod_b = (const float*)d_in[4];
  const float* w     = (const float*)d_in[5];
  const float* b     = (const float*)d_in[6];
  const float* gamma = (const float*)d_in[7];
  const float* beta  = (const float*)d_in[8];
  float* out = (float*)d_out;
  float* ws  = (float*)d_ws;

  unsigned short* xt  = (unsigned short*)(ws + XT_OFF);
  unsigned short* wbtA = (unsigned short*)(ws + WBTA_OFF);
  unsigned short* wbtB = (unsigned short*)(ws + WBTB_OFF);
  float* stat  = ws + STAT_OFF;

  prep_kernel<<<240, 256, 0, stream>>>(off_w, mod_w, w, wbtA, wbtB, stat);
  xform_kernel<<<512, 256, 0, stream>>>(x, xt);
  fused_dconv_kernel<<<1024, 256, 0, stream>>>(xt, wbtA, wbtB, off_b, mod_b, b, out, stat);
  bnrelu_kernel<<<8192, 256, 0, stream>>>(out, stat, gamma, beta);
}

// Round 8
// 232.225 us; speedup vs baseline: 1.0631x; 1.0631x over previous
//
#include <hip/hip_runtime.h>
#include <math.h>

// Problem constants: B=8, C=64 (in), OC=64 (out), H=W=128, K=3x3=9, PAD=1.
#define Hn 128
#define Wn 128
#define HW 16384
#define NPIX 131072
#define EPSv 1e-5f

// ws layout (floats)
#define XT_OFF   0            // x_t bf16 channels-last [b][y][x][c]: 8388608 shorts = 4194304 floats
#define WBTA_OFF 4194304      // 20480 shorts = 10240 floats
#define WBTB_OFF 4204544      // 40960 shorts = 20480 floats
#define STAT_OFF 4225024      // 128 (sum[64], sumsq[64])

// R18 (this round): un-bundle R17. The asm 16-deep burst SPILLED (WRITE
// +11.7MB scratch, fused 117->141us) -- 4th failed attempt at widening the
// gather window; R12/R16's ~4-deep schedule is the phase-3 local optimum.
// Keep ONLY R17's good half: stats fused into the epilogue (registers-only
// after the MFMA loop) -> stats2 dispatch + its 33.5MB pass deleted.
// Phase 1/2/3 are verbatim R16 (fused measured 117.3us).

typedef short s16x8 __attribute__((ext_vector_type(8)));
typedef unsigned short u16x4 __attribute__((ext_vector_type(4)));
typedef float f32x4 __attribute__((ext_vector_type(4)));
typedef unsigned int u32x4 __attribute__((ext_vector_type(4)));

__device__ __forceinline__ unsigned short f2bf(float f) {
  unsigned u = __float_as_uint(f);
  return (unsigned short)((u + 0x7fffu + ((u >> 16) & 1u)) >> 16);  // RNE
}
__device__ __forceinline__ float bf2f(unsigned short s) {
  return __uint_as_float((unsigned)s << 16);
}
__device__ __forceinline__ unsigned cvt_pk_bf16(float lo, float hi) {
  unsigned r;
  asm("v_cvt_pk_bf16_f32 %0, %1, %2" : "=v"(r) : "v"(lo), "v"(hi));
  return r;
}

// ---------------- prep: pack weights into MFMA operand order; zero stat ----------------
__global__ __launch_bounds__(256) void prep_kernel(
    const float* __restrict__ off_w, const float* __restrict__ mod_w,
    const float* __restrict__ w, unsigned short* __restrict__ wbtA,
    unsigned short* __restrict__ wbtB, float* __restrict__ stat) {
  int i = blockIdx.x * 256 + threadIdx.x;
  if (i < 128) stat[i] = 0.f;
  if (i < 20480) {
    // wbtA: A-operand (weights as rows) for phase 1 of the fused kernel.
    int e = i & 31, oc = (i >> 5) & 31, it = i >> 10;
    int tp = it % 5, chunk = it / 5;
    int tap = tp * 2 + (e >> 4);
    int c = (chunk << 4) + (e & 15);
    float v = 0.f;
    if (tap < 9) {
      if (oc < 18) v = off_w[(oc * 64 + c) * 9 + tap];
      else if (oc < 27) v = mod_w[((oc - 18) * 64 + c) * 9 + tap];
    }
    wbtA[i] = f2bf(v);
  } else if (i < 20480 + 40960) {
    // wbtB: B-operand fragments for phase 3 (deform).
    // index = ((it*4 + nt)*64 + lane)*8 + j
    // value = w[oc = nt*16 + (lane&15)][c][tap], where
    //   tap = (it%5)*2 + (lane>>5), c = (it/5)*16 + ((lane>>4)&1)*8 + j
    int j = i - 20480;
    int j3 = j & 7;
    int l = (j >> 3) & 63;
    int nt = (j >> 9) & 3;
    int it = j >> 11;
    int tp = it % 5, chunk = it / 5;
    int tap = tp * 2 + (l >> 5);
    int c = (chunk << 4) + (((l >> 4) & 1) << 3) + j3;
    int oc = (nt << 4) + (l & 15);
    float v = (tap < 9) ? w[(oc * 64 + c) * 9 + tap] : 0.f;
    wbtB[j] = f2bf(v);
  }
}

// ---------------- xform: x (NCHW fp32) -> x_t (NHWC bf16) ----------------
__global__ __launch_bounds__(256) void xform_kernel(
    const float* __restrict__ x, unsigned short* __restrict__ xt) {
  int blk = blockIdx.x;                       // 512 blocks
  int b = blk & 7;
  int hw = ((blk >> 3) << 8) + threadIdx.x;   // 0..16383
  const float* xb = x + ((size_t)(b << 6) << 14) + hw;
  unsigned short* o = xt + (((size_t)(b << 14)) + hw) * 64;
#pragma unroll
  for (int g = 0; g < 8; ++g) {
    float v[8];
#pragma unroll
    for (int j = 0; j < 8; ++j) v[j] = xb[(size_t)((g << 3) + j) << 14];
    s16x8 pk;
#pragma unroll
    for (int j = 0; j < 8; ++j) pk[j] = (short)f2bf(v[j]);
    *(s16x8*)(o + (g << 3)) = pk;
  }
}

// ---------------- fused kernel: convA (->LDS) + geometry + deform MFMA + stats ----------------
__global__ __launch_bounds__(256, 4) void fused_dconv_kernel(
    const unsigned short* __restrict__ xt, const unsigned short* __restrict__ wbtA,
    const unsigned short* __restrict__ wbtB,
    const float* __restrict__ off_b, const float* __restrict__ mod_b,
    const float* __restrict__ bias, float* __restrict__ y,
    float* __restrict__ stat) {
  __shared__ float offm[27 * 128];              // 13824 B; reused for stats reduce at the end
  __shared__ unsigned short geow[9 * 128 * 4];  // 9216 B: w00,w01,w10,w11 bf16 (mask folded)
  __shared__ unsigned short geoi[9 * 128];      // 2304 B: ibase = rbase*128+cbase
  int t = threadIdx.x;
  int bx = blockIdx.x;                  // 1024 = 8 b x 128 h
  int b = bx & 7, h = bx >> 3;
  int lane = t & 63, wv = t >> 6;
  int ln = lane & 15, quad = (lane >> 4) & 3;
  int hw = h << 7;

  const unsigned short* xtb = xt + ((size_t)(b << 14)) * 64;

  // ===== phase 1: offset+mask conv via MFMA, results to LDS =====
  {
    int p0 = (wv << 5) + ln, p1 = p0 + 16;
    int s_ = quad >> 1, cj = (quad & 1) << 3;
    f32x4 acc1[2][2];
#pragma unroll
    for (int mt = 0; mt < 2; ++mt)
#pragma unroll
      for (int nt = 0; nt < 2; ++nt) acc1[mt][nt] = (f32x4){0.f, 0.f, 0.f, 0.f};

#pragma unroll 5
    for (int it = 0; it < 20; ++it) {
      int chunk = it / 5, tp = it - chunk * 5;
      int tap = tp * 2 + s_;
      s16x8 B0 = (s16x8){0, 0, 0, 0, 0, 0, 0, 0};
      s16x8 B1 = (s16x8){0, 0, 0, 0, 0, 0, 0, 0};
      if (tap < 9) {
        int gy = h + tap / 3 - 1;
        if (gy >= 0 && gy < Hn) {
          const unsigned short* rowp = xtb + ((size_t)(gy << 7)) * 64 + (chunk << 4) + cj;
          int gx0 = p0 + tap % 3 - 1;
          int gx1 = p1 + tap % 3 - 1;
          if (gx0 >= 0 && gx0 < Wn) B0 = *(const s16x8*)(rowp + (gx0 << 6));
          if (gx1 >= 0 && gx1 < Wn) B1 = *(const s16x8*)(rowp + (gx1 << 6));
        }
      }
#pragma unroll
      for (int mt = 0; mt < 2; ++mt) {
        s16x8 A = *(const s16x8*)(wbtA + (size_t)((it << 5) + (mt << 4) + ln) * 32 + (quad << 3));
        acc1[mt][0] = __builtin_amdgcn_mfma_f32_16x16x32_bf16(A, B0, acc1[mt][0], 0, 0, 0);
        acc1[mt][1] = __builtin_amdgcn_mfma_f32_16x16x32_bf16(A, B1, acc1[mt][1], 0, 0, 0);
      }
    }

#pragma unroll
    for (int mt = 0; mt < 2; ++mt)
#pragma unroll
      for (int r = 0; r < 4; ++r) {
        int oc = (mt << 4) + (quad << 2) + r;
#pragma unroll
        for (int nt = 0; nt < 2; ++nt) {
          int px = (wv << 5) + (nt << 4) + ln;
          float val = acc1[mt][nt][r];
          if (oc < 18) {
            offm[(oc << 7) + px] = val + off_b[oc];
          } else if (oc < 27) {
            float z = val + mod_b[oc - 18];
            offm[(oc << 7) + px] = 2.f / (1.f + expf(-z));
          }
        }
      }
  }
  __syncthreads();

  // ===== phase 2: geometry for 128 px x 9 taps from LDS =====
  for (int i = t; i < 1152; i += 256) {
    int tap = i >> 7, p2 = i & 127;
    float dy = offm[((2 * tap) << 7) + p2];
    float dx = offm[((2 * tap + 1) << 7) + p2];
    float m = offm[((18 + tap) << 7) + p2];
    float py = dy + (float)(h + tap / 3 - 1);
    float pxf = dx + (float)(p2 + tap % 3 - 1);
    float y0f = floorf(py), x0f = floorf(pxf);
    float ly = py - y0f, lx = pxf - x0f;
    int y0 = (int)y0f, x0 = (int)x0f;
    int y1 = y0 + 1, x1 = x0 + 1;
    float fy0 = (y0 >= 0 && y0 < Hn) ? 1.f : 0.f;
    float fy1 = (y1 >= 0 && y1 < Hn) ? 1.f : 0.f;
    float fx0 = (x0 >= 0 && x0 < Wn) ? 1.f : 0.f;
    float fx1 = (x1 >= 0 && x1 < Wn) ? 1.f : 0.f;
    float ax0 = (1.f - lx) * fx0, ax1 = lx * fx1;
    float ay0 = (1.f - ly) * fy0 * m, ay1 = ly * fy1 * m;
    int cy0 = min(max(y0, 0), Hn - 1), cy1 = min(max(y1, 0), Hn - 1);
    int cx0 = min(max(x0, 0), Wn - 1), cx1 = min(max(x1, 0), Wn - 1);
    int cbase = min(cx0, Wn - 2), rbase = min(cy0, Hn - 2);
    float gx0 = (cx0 == cbase ? ax0 : 0.f) + (cx1 == cbase ? ax1 : 0.f);
    float gx1 = (cx0 == cbase + 1 ? ax0 : 0.f) + (cx1 == cbase + 1 ? ax1 : 0.f);
    float gy0 = (cy0 == rbase ? ay0 : 0.f) + (cy1 == rbase ? ay1 : 0.f);
    float gy1 = (cy0 == rbase + 1 ? ay0 : 0.f) + (cy1 == rbase + 1 ? ay1 : 0.f);
    unsigned short* gw = geow + i * 4;
    gw[0] = f2bf(gy0 * gx0);
    gw[1] = f2bf(gy0 * gx1);
    gw[2] = f2bf(gy1 * gx0);
    gw[3] = f2bf(gy1 * gx1);
    geoi[i] = (unsigned short)((rbase << 7) + cbase);
  }
  __syncthreads();

  // ===== phase 3: deform MFMA (verbatim R16 structure, 117.3us measured) =====
  int l4 = ln;
  int s4 = lane >> 4;        // k-slice 0..3
  int tapS = lane >> 5;      // which tap of the pair
  int chalf = s4 & 1;        // which 8ch half of the 16ch chunk

  f32x4 acc[2][4];  // [m-tile (px 16)][n-tile (oc 16)]
#pragma unroll
  for (int m = 0; m < 2; ++m)
#pragma unroll
    for (int n = 0; n < 4; ++n) acc[m][n] = (f32x4){0.f, 0.f, 0.f, 0.f};

  for (int tp = 0; tp < 5; ++tp) {
    int tap = tp * 2 + tapS;
    bool live = (tap < 9);
    float w00[2], w01[2], w10[2], w11[2];
    const unsigned short* cpb[2];
#pragma unroll
    for (int m = 0; m < 2; ++m) {
      if (live) {
        int px = (wv << 5) + (m << 4) + l4;
        int gidx = (tap << 7) + px;
        u16x4 wq = *(const u16x4*)(geow + gidx * 4);
        unsigned ib = geoi[gidx];
        w00[m] = bf2f(wq[0]);
        w01[m] = bf2f(wq[1]);
        w10[m] = bf2f(wq[2]);
        w11[m] = bf2f(wq[3]);
        cpb[m] = xtb + (size_t)ib * 64 + (chalf << 3);
      } else {
        cpb[m] = xtb;
        w00[m] = w01[m] = w10[m] = w11[m] = 0.f;
      }
    }
#pragma unroll 2
    for (int chunk = 0; chunk < 4; ++chunk) {
      int it = chunk * 5 + tp;
      s16x8 A[2];
#pragma unroll
      for (int m = 0; m < 2; ++m) {
        if (live) {
          const unsigned short* cp = cpb[m] + (chunk << 4);
          s16x8 c00 = *(const s16x8*)(cp);
          s16x8 c01 = *(const s16x8*)(cp + 64);
          s16x8 c10 = *(const s16x8*)(cp + 8192);
          s16x8 c11 = *(const s16x8*)(cp + 8192 + 64);
          u32x4 au;
#pragma unroll
          for (int jj = 0; jj < 4; ++jj) {
            float v0 = w00[m] * bf2f((unsigned short)c00[2 * jj]) +
                       w01[m] * bf2f((unsigned short)c01[2 * jj]) +
                       w10[m] * bf2f((unsigned short)c10[2 * jj]) +
                       w11[m] * bf2f((unsigned short)c11[2 * jj]);
            float v1 = w00[m] * bf2f((unsigned short)c00[2 * jj + 1]) +
                       w01[m] * bf2f((unsigned short)c01[2 * jj + 1]) +
                       w10[m] * bf2f((unsigned short)c10[2 * jj + 1]) +
                       w11[m] * bf2f((unsigned short)c11[2 * jj + 1]);
            au[jj] = cvt_pk_bf16(v0, v1);
          }
          A[m] = __builtin_bit_cast(s16x8, au);
        } else {
          A[m] = (s16x8){0, 0, 0, 0, 0, 0, 0, 0};
        }
      }
      const unsigned short* wb = wbtB + (((size_t)it) << 11) + (lane << 3);
#pragma unroll
      for (int n = 0; n < 4; ++n) {
        s16x8 Bf = *(const s16x8*)(wb + (n << 9));
        acc[0][n] = __builtin_amdgcn_mfma_f32_16x16x32_bf16(A[0], Bf, acc[0][n], 0, 0, 0);
        acc[1][n] = __builtin_amdgcn_mfma_f32_16x16x32_bf16(A[1], Bf, acc[1][n], 0, 0, 0);
      }
    }
  }

  // ===== epilogue: bias + store + per-channel stats (fused; registers-only cost) =====
  float sac[4], ssc[4];
#pragma unroll
  for (int n = 0; n < 4; ++n) { sac[n] = 0.f; ssc[n] = 0.f; }
#pragma unroll
  for (int m = 0; m < 2; ++m) {
    int px0 = (wv << 5) + (m << 4) + (s4 << 2);
#pragma unroll
    for (int n = 0; n < 4; ++n) {
      int oc = (n << 4) + l4;
      float bv = bias[oc];
      float4 o;
      o.x = acc[m][n][0] + bv;
      o.y = acc[m][n][1] + bv;
      o.z = acc[m][n][2] + bv;
      o.w = acc[m][n][3] + bv;
      sac[n] += o.x + o.y + o.z + o.w;
      ssc[n] += o.x * o.x + o.y * o.y + o.z * o.z + o.w * o.w;
      *(float4*)(y + (((size_t)(b << 6) + oc) << 14) + hw + px0) = o;
    }
  }
  // reduce over the 4 k-slice lanes (same l4, different s4): xor 16, 32
#pragma unroll
  for (int n = 0; n < 4; ++n) {
    sac[n] += __shfl_xor(sac[n], 16);
    sac[n] += __shfl_xor(sac[n], 32);
    ssc[n] += __shfl_xor(ssc[n], 16);
    ssc[n] += __shfl_xor(ssc[n], 32);
  }
  if (lane < 16) {
#pragma unroll
    for (int n = 0; n < 4; ++n) {
      int oc = (n << 4) + lane;
      offm[(wv << 6) + oc] = sac[n];
      offm[256 + (wv << 6) + oc] = ssc[n];
    }
  }
  __syncthreads();
  if (t < 64) {
    float S = offm[t] + offm[64 + t] + offm[128 + t] + offm[192 + t];
    float SS = offm[256 + t] + offm[320 + t] + offm[384 + t] + offm[448 + t];
    atomicAdd(stat + t, S);
    atomicAdd(stat + 64 + t, SS);
  }
}

// ---------------- kernel D: batchnorm scale/shift + relu, in place ----------------
__global__ __launch_bounds__(256) void bnrelu_kernel(
    float* __restrict__ y, const float* __restrict__ stat,
    const float* __restrict__ gamma, const float* __restrict__ beta) {
  float4* y4 = (float4*)y;
  for (int i = blockIdx.x * 256 + threadIdx.x; i < 2097152; i += gridDim.x * 256) {
    int c = (i >> 12) & 63;
    float mean = stat[c] * (1.f / (float)NPIX);
    float var = stat[64 + c] * (1.f / (float)NPIX) - mean * mean;
    float r = rsqrtf(var + EPSv);
    float g = gamma[c] * r;
    float bt = beta[c] - mean * g;
    float4 v = y4[i];
    v.x = fmaxf(v.x * g + bt, 0.f);
    v.y = fmaxf(v.y * g + bt, 0.f);
    v.z = fmaxf(v.z * g + bt, 0.f);
    v.w = fmaxf(v.w * g + bt, 0.f);
    y4[i] = v;
  }
}

extern "C" void kernel_launch(void* const* d_in, const int* in_sizes, int n_in,
                              void* d_out, int out_size, void* d_ws, size_t ws_size,
                              hipStream_t stream) {
  const float* x     = (const float*)d_in[0];
  const float* off_w = (const float*)d_in[1];
  const float* off_b = (const float*)d_in[2];
  const float* mod_w = (const float*)d_in[3];
  const float* mod_b = (const float*)d_in[4];
  const float* w     = (const float*)d_in[5];
  const float* b     = (const float*)d_in[6];
  const float* gamma = (const float*)d_in[7];
  const float* beta  = (const float*)d_in[8];
  float* out = (float*)d_out;
  float* ws  = (float*)d_ws;

  unsigned short* xt  = (unsigned short*)(ws + XT_OFF);
  unsigned short* wbtA = (unsigned short*)(ws + WBTA_OFF);
  unsigned short* wbtB = (unsigned short*)(ws + WBTB_OFF);
  float* stat  = ws + STAT_OFF;

  prep_kernel<<<240, 256, 0, stream>>>(off_w, mod_w, w, wbtA, wbtB, stat);
  xform_kernel<<<512, 256, 0, stream>>>(x, xt);
  fused_dconv_kernel<<<1024, 256, 0, stream>>>(xt, wbtA, wbtB, off_b, mod_b, b, out, stat);
  bnrelu_kernel<<<8192, 256, 0, stream>>>(out, stat, gamma, beta);
}

// Round 9
// 216.003 us; speedup vs baseline: 1.1430x; 1.0751x over previous
//
#include <hip/hip_runtime.h>
#include <math.h>

// Problem constants: B=8, C=64 (in), OC=64 (out), H=W=128, K=3x3=9, PAD=1.
#define Hn 128
#define Wn 128
#define HW 16384
#define NPIX 131072
#define EPSv 1e-5f

// ws layout (floats)
#define XT_OFF   0            // x_t bf16 channels-last [b][y][x][c]: 8388608 shorts = 4194304 floats
#define WBTA_OFF 4194304      // 20480 shorts = 10240 floats
#define WBTB_OFF 4204544      // 40960 shorts = 20480 floats
#define STAT_OFF 4225024      // 8 replicas x 128 (sum[64], sumsq[64]) = 1024 floats

// R19 (this round): R18's stats epilogue cost +9.3us = atomic TAIL, not
// compute: 1024 blocks x 128 atomicAdd onto the SAME 128 addresses =
// 1024-way same-address L2 serialization (~12us, matches). Fix per G12:
// 8-way replicated stat slots (block bx&7 -> own 128-float slot, contention
// /8); bnrelu reduces the 8 replicas once per block into an LDS g/bt table.
// Also: prep merged into xform (-1 dispatch). Phases 1/2/3 verbatim R16.

typedef short s16x8 __attribute__((ext_vector_type(8)));
typedef unsigned short u16x4 __attribute__((ext_vector_type(4)));
typedef float f32x4 __attribute__((ext_vector_type(4)));
typedef unsigned int u32x4 __attribute__((ext_vector_type(4)));

__device__ __forceinline__ unsigned short f2bf(float f) {
  unsigned u = __float_as_uint(f);
  return (unsigned short)((u + 0x7fffu + ((u >> 16) & 1u)) >> 16);  // RNE
}
__device__ __forceinline__ float bf2f(unsigned short s) {
  return __uint_as_float((unsigned)s << 16);
}
__device__ __forceinline__ unsigned cvt_pk_bf16(float lo, float hi) {
  unsigned r;
  asm("v_cvt_pk_bf16_f32 %0, %1, %2" : "=v"(r) : "v"(lo), "v"(hi));
  return r;
}

// ---------------- merged prep(+stat zero) + xform kernel ----------------
// blocks 0..511: xform x (NCHW fp32) -> x_t (NHWC bf16). blocks 512..751: weight pack.
__global__ __launch_bounds__(256) void prep_xform_kernel(
    const float* __restrict__ x, unsigned short* __restrict__ xt,
    const float* __restrict__ off_w, const float* __restrict__ mod_w,
    const float* __restrict__ w, unsigned short* __restrict__ wbtA,
    unsigned short* __restrict__ wbtB, float* __restrict__ stat) {
  int blk = blockIdx.x;
  if (blk < 512) {
    int b = blk & 7;
    int hw = ((blk >> 3) << 8) + threadIdx.x;   // 0..16383
    const float* xb = x + ((size_t)(b << 6) << 14) + hw;
    unsigned short* o = xt + (((size_t)(b << 14)) + hw) * 64;
#pragma unroll
    for (int g = 0; g < 8; ++g) {
      float v[8];
#pragma unroll
      for (int j = 0; j < 8; ++j) v[j] = xb[(size_t)((g << 3) + j) << 14];
      s16x8 pk;
#pragma unroll
      for (int j = 0; j < 8; ++j) pk[j] = (short)f2bf(v[j]);
      *(s16x8*)(o + (g << 3)) = pk;
    }
    return;
  }
  int i = ((blk - 512) << 8) + threadIdx.x;
  if (i < 1024) stat[i] = 0.f;   // 8 replica slots
  if (i < 20480) {
    // wbtA: A-operand (weights as rows) for phase 1 of the fused kernel.
    int e = i & 31, oc = (i >> 5) & 31, it = i >> 10;
    int tp = it % 5, chunk = it / 5;
    int tap = tp * 2 + (e >> 4);
    int c = (chunk << 4) + (e & 15);
    float v = 0.f;
    if (tap < 9) {
      if (oc < 18) v = off_w[(oc * 64 + c) * 9 + tap];
      else if (oc < 27) v = mod_w[((oc - 18) * 64 + c) * 9 + tap];
    }
    wbtA[i] = f2bf(v);
  } else if (i < 20480 + 40960) {
    // wbtB: B-operand fragments for phase 3 (deform).
    // index = ((it*4 + nt)*64 + lane)*8 + j
    // value = w[oc = nt*16 + (lane&15)][c][tap], where
    //   tap = (it%5)*2 + (lane>>5), c = (it/5)*16 + ((lane>>4)&1)*8 + j
    int j = i - 20480;
    int j3 = j & 7;
    int l = (j >> 3) & 63;
    int nt = (j >> 9) & 3;
    int it = j >> 11;
    int tp = it % 5, chunk = it / 5;
    int tap = tp * 2 + (l >> 5);
    int c = (chunk << 4) + (((l >> 4) & 1) << 3) + j3;
    int oc = (nt << 4) + (l & 15);
    float v = (tap < 9) ? w[(oc * 64 + c) * 9 + tap] : 0.f;
    wbtB[j] = f2bf(v);
  }
}

// ---------------- fused kernel: convA (->LDS) + geometry + deform MFMA + stats ----------------
__global__ __launch_bounds__(256, 4) void fused_dconv_kernel(
    const unsigned short* __restrict__ xt, const unsigned short* __restrict__ wbtA,
    const unsigned short* __restrict__ wbtB,
    const float* __restrict__ off_b, const float* __restrict__ mod_b,
    const float* __restrict__ bias, float* __restrict__ y,
    float* __restrict__ stat) {
  __shared__ float offm[27 * 128];              // 13824 B; reused for stats reduce at the end
  __shared__ unsigned short geow[9 * 128 * 4];  // 9216 B: w00,w01,w10,w11 bf16 (mask folded)
  __shared__ unsigned short geoi[9 * 128];      // 2304 B: ibase = rbase*128+cbase
  int t = threadIdx.x;
  int bx = blockIdx.x;                  // 1024 = 8 b x 128 h
  int b = bx & 7, h = bx >> 3;
  int lane = t & 63, wv = t >> 6;
  int ln = lane & 15, quad = (lane >> 4) & 3;
  int hw = h << 7;

  const unsigned short* xtb = xt + ((size_t)(b << 14)) * 64;

  // ===== phase 1: offset+mask conv via MFMA, results to LDS =====
  {
    int p0 = (wv << 5) + ln, p1 = p0 + 16;
    int s_ = quad >> 1, cj = (quad & 1) << 3;
    f32x4 acc1[2][2];
#pragma unroll
    for (int mt = 0; mt < 2; ++mt)
#pragma unroll
      for (int nt = 0; nt < 2; ++nt) acc1[mt][nt] = (f32x4){0.f, 0.f, 0.f, 0.f};

#pragma unroll 5
    for (int it = 0; it < 20; ++it) {
      int chunk = it / 5, tp = it - chunk * 5;
      int tap = tp * 2 + s_;
      s16x8 B0 = (s16x8){0, 0, 0, 0, 0, 0, 0, 0};
      s16x8 B1 = (s16x8){0, 0, 0, 0, 0, 0, 0, 0};
      if (tap < 9) {
        int gy = h + tap / 3 - 1;
        if (gy >= 0 && gy < Hn) {
          const unsigned short* rowp = xtb + ((size_t)(gy << 7)) * 64 + (chunk << 4) + cj;
          int gx0 = p0 + tap % 3 - 1;
          int gx1 = p1 + tap % 3 - 1;
          if (gx0 >= 0 && gx0 < Wn) B0 = *(const s16x8*)(rowp + (gx0 << 6));
          if (gx1 >= 0 && gx1 < Wn) B1 = *(const s16x8*)(rowp + (gx1 << 6));
        }
      }
#pragma unroll
      for (int mt = 0; mt < 2; ++mt) {
        s16x8 A = *(const s16x8*)(wbtA + (size_t)((it << 5) + (mt << 4) + ln) * 32 + (quad << 3));
        acc1[mt][0] = __builtin_amdgcn_mfma_f32_16x16x32_bf16(A, B0, acc1[mt][0], 0, 0, 0);
        acc1[mt][1] = __builtin_amdgcn_mfma_f32_16x16x32_bf16(A, B1, acc1[mt][1], 0, 0, 0);
      }
    }

#pragma unroll
    for (int mt = 0; mt < 2; ++mt)
#pragma unroll
      for (int r = 0; r < 4; ++r) {
        int oc = (mt << 4) + (quad << 2) + r;
#pragma unroll
        for (int nt = 0; nt < 2; ++nt) {
          int px = (wv << 5) + (nt << 4) + ln;
          float val = acc1[mt][nt][r];
          if (oc < 18) {
            offm[(oc << 7) + px] = val + off_b[oc];
          } else if (oc < 27) {
            float z = val + mod_b[oc - 18];
            offm[(oc << 7) + px] = 2.f / (1.f + expf(-z));
          }
        }
      }
  }
  __syncthreads();

  // ===== phase 2: geometry for 128 px x 9 taps from LDS =====
  for (int i = t; i < 1152; i += 256) {
    int tap = i >> 7, p2 = i & 127;
    float dy = offm[((2 * tap) << 7) + p2];
    float dx = offm[((2 * tap + 1) << 7) + p2];
    float m = offm[((18 + tap) << 7) + p2];
    float py = dy + (float)(h + tap / 3 - 1);
    float pxf = dx + (float)(p2 + tap % 3 - 1);
    float y0f = floorf(py), x0f = floorf(pxf);
    float ly = py - y0f, lx = pxf - x0f;
    int y0 = (int)y0f, x0 = (int)x0f;
    int y1 = y0 + 1, x1 = x0 + 1;
    float fy0 = (y0 >= 0 && y0 < Hn) ? 1.f : 0.f;
    float fy1 = (y1 >= 0 && y1 < Hn) ? 1.f : 0.f;
    float fx0 = (x0 >= 0 && x0 < Wn) ? 1.f : 0.f;
    float fx1 = (x1 >= 0 && x1 < Wn) ? 1.f : 0.f;
    float ax0 = (1.f - lx) * fx0, ax1 = lx * fx1;
    float ay0 = (1.f - ly) * fy0 * m, ay1 = ly * fy1 * m;
    int cy0 = min(max(y0, 0), Hn - 1), cy1 = min(max(y1, 0), Hn - 1);
    int cx0 = min(max(x0, 0), Wn - 1), cx1 = min(max(x1, 0), Wn - 1);
    int cbase = min(cx0, Wn - 2), rbase = min(cy0, Hn - 2);
    float gx0 = (cx0 == cbase ? ax0 : 0.f) + (cx1 == cbase ? ax1 : 0.f);
    float gx1 = (cx0 == cbase + 1 ? ax0 : 0.f) + (cx1 == cbase + 1 ? ax1 : 0.f);
    float gy0 = (cy0 == rbase ? ay0 : 0.f) + (cy1 == rbase ? ay1 : 0.f);
    float gy1 = (cy0 == rbase + 1 ? ay0 : 0.f) + (cy1 == rbase + 1 ? ay1 : 0.f);
    unsigned short* gw = geow + i * 4;
    gw[0] = f2bf(gy0 * gx0);
    gw[1] = f2bf(gy0 * gx1);
    gw[2] = f2bf(gy1 * gx0);
    gw[3] = f2bf(gy1 * gx1);
    geoi[i] = (unsigned short)((rbase << 7) + cbase);
  }
  __syncthreads();

  // ===== phase 3: deform MFMA (verbatim R16 structure, 117.3us measured) =====
  int l4 = ln;
  int s4 = lane >> 4;        // k-slice 0..3
  int tapS = lane >> 5;      // which tap of the pair
  int chalf = s4 & 1;        // which 8ch half of the 16ch chunk

  f32x4 acc[2][4];  // [m-tile (px 16)][n-tile (oc 16)]
#pragma unroll
  for (int m = 0; m < 2; ++m)
#pragma unroll
    for (int n = 0; n < 4; ++n) acc[m][n] = (f32x4){0.f, 0.f, 0.f, 0.f};

  for (int tp = 0; tp < 5; ++tp) {
    int tap = tp * 2 + tapS;
    bool live = (tap < 9);
    float w00[2], w01[2], w10[2], w11[2];
    const unsigned short* cpb[2];
#pragma unroll
    for (int m = 0; m < 2; ++m) {
      if (live) {
        int px = (wv << 5) + (m << 4) + l4;
        int gidx = (tap << 7) + px;
        u16x4 wq = *(const u16x4*)(geow + gidx * 4);
        unsigned ib = geoi[gidx];
        w00[m] = bf2f(wq[0]);
        w01[m] = bf2f(wq[1]);
        w10[m] = bf2f(wq[2]);
        w11[m] = bf2f(wq[3]);
        cpb[m] = xtb + (size_t)ib * 64 + (chalf << 3);
      } else {
        cpb[m] = xtb;
        w00[m] = w01[m] = w10[m] = w11[m] = 0.f;
      }
    }
#pragma unroll 2
    for (int chunk = 0; chunk < 4; ++chunk) {
      int it = chunk * 5 + tp;
      s16x8 A[2];
#pragma unroll
      for (int m = 0; m < 2; ++m) {
        if (live) {
          const unsigned short* cp = cpb[m] + (chunk << 4);
          s16x8 c00 = *(const s16x8*)(cp);
          s16x8 c01 = *(const s16x8*)(cp + 64);
          s16x8 c10 = *(const s16x8*)(cp + 8192);
          s16x8 c11 = *(const s16x8*)(cp + 8192 + 64);
          u32x4 au;
#pragma unroll
          for (int jj = 0; jj < 4; ++jj) {
            float v0 = w00[m] * bf2f((unsigned short)c00[2 * jj]) +
                       w01[m] * bf2f((unsigned short)c01[2 * jj]) +
                       w10[m] * bf2f((unsigned short)c10[2 * jj]) +
                       w11[m] * bf2f((unsigned short)c11[2 * jj]);
            float v1 = w00[m] * bf2f((unsigned short)c00[2 * jj + 1]) +
                       w01[m] * bf2f((unsigned short)c01[2 * jj + 1]) +
                       w10[m] * bf2f((unsigned short)c10[2 * jj + 1]) +
                       w11[m] * bf2f((unsigned short)c11[2 * jj + 1]);
            au[jj] = cvt_pk_bf16(v0, v1);
          }
          A[m] = __builtin_bit_cast(s16x8, au);
        } else {
          A[m] = (s16x8){0, 0, 0, 0, 0, 0, 0, 0};
        }
      }
      const unsigned short* wb = wbtB + (((size_t)it) << 11) + (lane << 3);
#pragma unroll
      for (int n = 0; n < 4; ++n) {
        s16x8 Bf = *(const s16x8*)(wb + (n << 9));
        acc[0][n] = __builtin_amdgcn_mfma_f32_16x16x32_bf16(A[0], Bf, acc[0][n], 0, 0, 0);
        acc[1][n] = __builtin_amdgcn_mfma_f32_16x16x32_bf16(A[1], Bf, acc[1][n], 0, 0, 0);
      }
    }
  }

  // ===== epilogue: bias + store + per-channel stats (8-way replicated atomics) =====
  float sac[4], ssc[4];
#pragma unroll
  for (int n = 0; n < 4; ++n) { sac[n] = 0.f; ssc[n] = 0.f; }
#pragma unroll
  for (int m = 0; m < 2; ++m) {
    int px0 = (wv << 5) + (m << 4) + (s4 << 2);
#pragma unroll
    for (int n = 0; n < 4; ++n) {
      int oc = (n << 4) + l4;
      float bv = bias[oc];
      float4 o;
      o.x = acc[m][n][0] + bv;
      o.y = acc[m][n][1] + bv;
      o.z = acc[m][n][2] + bv;
      o.w = acc[m][n][3] + bv;
      sac[n] += o.x + o.y + o.z + o.w;
      ssc[n] += o.x * o.x + o.y * o.y + o.z * o.z + o.w * o.w;
      *(float4*)(y + (((size_t)(b << 6) + oc) << 14) + hw + px0) = o;
    }
  }
  // reduce over the 4 k-slice lanes (same l4, different s4): xor 16, 32
#pragma unroll
  for (int n = 0; n < 4; ++n) {
    sac[n] += __shfl_xor(sac[n], 16);
    sac[n] += __shfl_xor(sac[n], 32);
    ssc[n] += __shfl_xor(ssc[n], 16);
    ssc[n] += __shfl_xor(ssc[n], 32);
  }
  if (lane < 16) {
#pragma unroll
    for (int n = 0; n < 4; ++n) {
      int oc = (n << 4) + lane;
      offm[(wv << 6) + oc] = sac[n];
      offm[256 + (wv << 6) + oc] = ssc[n];
    }
  }
  __syncthreads();
  if (t < 64) {
    float S = offm[t] + offm[64 + t] + offm[128 + t] + offm[192 + t];
    float SS = offm[256 + t] + offm[320 + t] + offm[384 + t] + offm[448 + t];
    float* sb = stat + ((bx & 7) << 7);   // replica slot: contention 1024 -> 128 per address
    atomicAdd(sb + t, S);
    atomicAdd(sb + 64 + t, SS);
  }
}

// ---------------- kernel D: batchnorm scale/shift + relu, in place ----------------
__global__ __launch_bounds__(256) void bnrelu_kernel(
    float* __restrict__ y, const float* __restrict__ stat,
    const float* __restrict__ gamma, const float* __restrict__ beta) {
  __shared__ float gs[64], bs[64];
  int t = threadIdx.x;
  if (t < 64) {
    float S = 0.f, SS = 0.f;
#pragma unroll
    for (int k = 0; k < 8; ++k) {
      S += stat[(k << 7) + t];
      SS += stat[(k << 7) + 64 + t];
    }
    float mean = S * (1.f / (float)NPIX);
    float var = SS * (1.f / (float)NPIX) - mean * mean;
    float r = rsqrtf(var + EPSv);
    float g = gamma[t] * r;
    gs[t] = g;
    bs[t] = beta[t] - mean * g;
  }
  __syncthreads();
  float4* y4 = (float4*)y;
  for (int i = blockIdx.x * 256 + t; i < 2097152; i += gridDim.x * 256) {
    int c = (i >> 12) & 63;
    float g = gs[c];
    float bt = bs[c];
    float4 v = y4[i];
    v.x = fmaxf(v.x * g + bt, 0.f);
    v.y = fmaxf(v.y * g + bt, 0.f);
    v.z = fmaxf(v.z * g + bt, 0.f);
    v.w = fmaxf(v.w * g + bt, 0.f);
    y4[i] = v;
  }
}

extern "C" void kernel_launch(void* const* d_in, const int* in_sizes, int n_in,
                              void* d_out, int out_size, void* d_ws, size_t ws_size,
                              hipStream_t stream) {
  const float* x     = (const float*)d_in[0];
  const float* off_w = (const float*)d_in[1];
  const float* off_b = (const float*)d_in[2];
  const float* mod_w = (const float*)d_in[3];
  const float* mod_b = (const float*)d_in[4];
  const float* w     = (const float*)d_in[5];
  const float* b     = (const float*)d_in[6];
  const float* gamma = (const float*)d_in[7];
  const float* beta  = (const float*)d_in[8];
  float* out = (float*)d_out;
  float* ws  = (float*)d_ws;

  unsigned short* xt  = (unsigned short*)(ws + XT_OFF);
  unsigned short* wbtA = (unsigned short*)(ws + WBTA_OFF);
  unsigned short* wbtB = (unsigned short*)(ws + WBTB_OFF);
  float* stat  = ws + STAT_OFF;

  prep_xform_kernel<<<752, 256, 0, stream>>>(x, xt, off_w, mod_w, w, wbtA, wbtB, stat);
  fused_dconv_kernel<<<1024, 256, 0, stream>>>(xt, wbtA, wbtB, off_b, mod_b, b, out, stat);
  bnrelu_kernel<<<8192, 256, 0, stream>>>(out, stat, gamma, beta);
}

// Round 12
// 215.274 us; speedup vs baseline: 1.1468x; 1.0034x over previous
//
#include <hip/hip_runtime.h>
#include <math.h>

// Problem constants: B=8, C=64 (in), OC=64 (out), H=W=128, K=3x3=9, PAD=1.
#define Hn 128
#define Wn 128
#define HW 16384
#define NPIX 131072
#define EPSv 1e-5f

// ws layout (floats)
#define XT_OFF   0            // x_t bf16 channels-last [b][y][x][c]: 8388608 shorts = 4194304 floats
#define WBTA_OFF 4194304      // 20480 shorts = 10240 floats
#define WBTB_OFF 4204544      // 40960 shorts = 20480 floats
#define STAT_OFF 4225024      // 8 replicas x 128 (sum[64], sumsq[64]) = 1024 floats

// R22 (this round): cooperative launch is DEAD in this harness -- R20/R21
// failed with BIT-IDENTICAL absmax (5.75 = max|ref|, i.e. output stayed
// memset-zero): hipLaunchCooperativeKernel is silently dropped under the
// harness's graph capture. Revert to R19 (passed, 216.0us, 3 plain
// dispatches) + two low-risk increments: (1) s_setprio(1/0) around the
// phase-3 MFMA cluster (independent-block regime = attn-like, T5 measured
// +4-7% there; first clean test on this kernel); (2) bnrelu grid 8192->2048
// with grid-stride (G11). Everything else byte-identical to R19.

typedef short s16x8 __attribute__((ext_vector_type(8)));
typedef unsigned short u16x4 __attribute__((ext_vector_type(4)));
typedef float f32x4 __attribute__((ext_vector_type(4)));
typedef unsigned int u32x4 __attribute__((ext_vector_type(4)));

__device__ __forceinline__ unsigned short f2bf(float f) {
  unsigned u = __float_as_uint(f);
  return (unsigned short)((u + 0x7fffu + ((u >> 16) & 1u)) >> 16);  // RNE
}
__device__ __forceinline__ float bf2f(unsigned short s) {
  return __uint_as_float((unsigned)s << 16);
}
__device__ __forceinline__ unsigned cvt_pk_bf16(float lo, float hi) {
  unsigned r;
  asm("v_cvt_pk_bf16_f32 %0, %1, %2" : "=v"(r) : "v"(lo), "v"(hi));
  return r;
}

// ---------------- merged prep(+stat zero) + xform kernel ----------------
// blocks 0..511: xform x (NCHW fp32) -> x_t (NHWC bf16). blocks 512..751: weight pack.
__global__ __launch_bounds__(256) void prep_xform_kernel(
    const float* __restrict__ x, unsigned short* __restrict__ xt,
    const float* __restrict__ off_w, const float* __restrict__ mod_w,
    const float* __restrict__ w, unsigned short* __restrict__ wbtA,
    unsigned short* __restrict__ wbtB, float* __restrict__ stat) {
  int blk = blockIdx.x;
  if (blk < 512) {
    int b = blk & 7;
    int hw = ((blk >> 3) << 8) + threadIdx.x;   // 0..16383
    const float* xb = x + ((size_t)(b << 6) << 14) + hw;
    unsigned short* o = xt + (((size_t)(b << 14)) + hw) * 64;
#pragma unroll
    for (int g = 0; g < 8; ++g) {
      float v[8];
#pragma unroll
      for (int j = 0; j < 8; ++j) v[j] = xb[(size_t)((g << 3) + j) << 14];
      s16x8 pk;
#pragma unroll
      for (int j = 0; j < 8; ++j) pk[j] = (short)f2bf(v[j]);
      *(s16x8*)(o + (g << 3)) = pk;
    }
    return;
  }
  int i = ((blk - 512) << 8) + threadIdx.x;
  if (i < 1024) stat[i] = 0.f;   // 8 replica slots
  if (i < 20480) {
    // wbtA: A-operand (weights as rows) for phase 1 of the fused kernel.
    int e = i & 31, oc = (i >> 5) & 31, it = i >> 10;
    int tp = it % 5, chunk = it / 5;
    int tap = tp * 2 + (e >> 4);
    int c = (chunk << 4) + (e & 15);
    float v = 0.f;
    if (tap < 9) {
      if (oc < 18) v = off_w[(oc * 64 + c) * 9 + tap];
      else if (oc < 27) v = mod_w[((oc - 18) * 64 + c) * 9 + tap];
    }
    wbtA[i] = f2bf(v);
  } else if (i < 20480 + 40960) {
    // wbtB: B-operand fragments for phase 3 (deform).
    // index = ((it*4 + nt)*64 + lane)*8 + j
    // value = w[oc = nt*16 + (lane&15)][c][tap], where
    //   tap = (it%5)*2 + (lane>>5), c = (it/5)*16 + ((lane>>4)&1)*8 + j
    int j = i - 20480;
    int j3 = j & 7;
    int l = (j >> 3) & 63;
    int nt = (j >> 9) & 3;
    int it = j >> 11;
    int tp = it % 5, chunk = it / 5;
    int tap = tp * 2 + (l >> 5);
    int c = (chunk << 4) + (((l >> 4) & 1) << 3) + j3;
    int oc = (nt << 4) + (l & 15);
    float v = (tap < 9) ? w[(oc * 64 + c) * 9 + tap] : 0.f;
    wbtB[j] = f2bf(v);
  }
}

// ---------------- fused kernel: convA (->LDS) + geometry + deform MFMA + stats ----------------
__global__ __launch_bounds__(256, 4) void fused_dconv_kernel(
    const unsigned short* __restrict__ xt, const unsigned short* __restrict__ wbtA,
    const unsigned short* __restrict__ wbtB,
    const float* __restrict__ off_b, const float* __restrict__ mod_b,
    const float* __restrict__ bias, float* __restrict__ y,
    float* __restrict__ stat) {
  __shared__ float offm[27 * 128];              // 13824 B; reused for stats reduce at the end
  __shared__ unsigned short geow[9 * 128 * 4];  // 9216 B: w00,w01,w10,w11 bf16 (mask folded)
  __shared__ unsigned short geoi[9 * 128];      // 2304 B: ibase = rbase*128+cbase
  int t = threadIdx.x;
  int bx = blockIdx.x;                  // 1024 = 8 b x 128 h
  int b = bx & 7, h = bx >> 3;
  int lane = t & 63, wv = t >> 6;
  int ln = lane & 15, quad = (lane >> 4) & 3;
  int hw = h << 7;

  const unsigned short* xtb = xt + ((size_t)(b << 14)) * 64;

  // ===== phase 1: offset+mask conv via MFMA, results to LDS =====
  {
    int p0 = (wv << 5) + ln, p1 = p0 + 16;
    int s_ = quad >> 1, cj = (quad & 1) << 3;
    f32x4 acc1[2][2];
#pragma unroll
    for (int mt = 0; mt < 2; ++mt)
#pragma unroll
      for (int nt = 0; nt < 2; ++nt) acc1[mt][nt] = (f32x4){0.f, 0.f, 0.f, 0.f};

#pragma unroll 5
    for (int it = 0; it < 20; ++it) {
      int chunk = it / 5, tp = it - chunk * 5;
      int tap = tp * 2 + s_;
      s16x8 B0 = (s16x8){0, 0, 0, 0, 0, 0, 0, 0};
      s16x8 B1 = (s16x8){0, 0, 0, 0, 0, 0, 0, 0};
      if (tap < 9) {
        int gy = h + tap / 3 - 1;
        if (gy >= 0 && gy < Hn) {
          const unsigned short* rowp = xtb + ((size_t)(gy << 7)) * 64 + (chunk << 4) + cj;
          int gx0 = p0 + tap % 3 - 1;
          int gx1 = p1 + tap % 3 - 1;
          if (gx0 >= 0 && gx0 < Wn) B0 = *(const s16x8*)(rowp + (gx0 << 6));
          if (gx1 >= 0 && gx1 < Wn) B1 = *(const s16x8*)(rowp + (gx1 << 6));
        }
      }
#pragma unroll
      for (int mt = 0; mt < 2; ++mt) {
        s16x8 A = *(const s16x8*)(wbtA + (size_t)((it << 5) + (mt << 4) + ln) * 32 + (quad << 3));
        acc1[mt][0] = __builtin_amdgcn_mfma_f32_16x16x32_bf16(A, B0, acc1[mt][0], 0, 0, 0);
        acc1[mt][1] = __builtin_amdgcn_mfma_f32_16x16x32_bf16(A, B1, acc1[mt][1], 0, 0, 0);
      }
    }

#pragma unroll
    for (int mt = 0; mt < 2; ++mt)
#pragma unroll
      for (int r = 0; r < 4; ++r) {
        int oc = (mt << 4) + (quad << 2) + r;
#pragma unroll
        for (int nt = 0; nt < 2; ++nt) {
          int px = (wv << 5) + (nt << 4) + ln;
          float val = acc1[mt][nt][r];
          if (oc < 18) {
            offm[(oc << 7) + px] = val + off_b[oc];
          } else if (oc < 27) {
            float z = val + mod_b[oc - 18];
            offm[(oc << 7) + px] = 2.f / (1.f + expf(-z));
          }
        }
      }
  }
  __syncthreads();

  // ===== phase 2: geometry for 128 px x 9 taps from LDS =====
  for (int i = t; i < 1152; i += 256) {
    int tap = i >> 7, p2 = i & 127;
    float dy = offm[((2 * tap) << 7) + p2];
    float dx = offm[((2 * tap + 1) << 7) + p2];
    float m = offm[((18 + tap) << 7) + p2];
    float py = dy + (float)(h + tap / 3 - 1);
    float pxf = dx + (float)(p2 + tap % 3 - 1);
    float y0f = floorf(py), x0f = floorf(pxf);
    float ly = py - y0f, lx = pxf - x0f;
    int y0 = (int)y0f, x0 = (int)x0f;
    int y1 = y0 + 1, x1 = x0 + 1;
    float fy0 = (y0 >= 0 && y0 < Hn) ? 1.f : 0.f;
    float fy1 = (y1 >= 0 && y1 < Hn) ? 1.f : 0.f;
    float fx0 = (x0 >= 0 && x0 < Wn) ? 1.f : 0.f;
    float fx1 = (x1 >= 0 && x1 < Wn) ? 1.f : 0.f;
    float ax0 = (1.f - lx) * fx0, ax1 = lx * fx1;
    float ay0 = (1.f - ly) * fy0 * m, ay1 = ly * fy1 * m;
    int cy0 = min(max(y0, 0), Hn - 1), cy1 = min(max(y1, 0), Hn - 1);
    int cx0 = min(max(x0, 0), Wn - 1), cx1 = min(max(x1, 0), Wn - 1);
    int cbase = min(cx0, Wn - 2), rbase = min(cy0, Hn - 2);
    float gx0 = (cx0 == cbase ? ax0 : 0.f) + (cx1 == cbase ? ax1 : 0.f);
    float gx1 = (cx0 == cbase + 1 ? ax0 : 0.f) + (cx1 == cbase + 1 ? ax1 : 0.f);
    float gy0 = (cy0 == rbase ? ay0 : 0.f) + (cy1 == rbase ? ay1 : 0.f);
    float gy1 = (cy0 == rbase + 1 ? ay0 : 0.f) + (cy1 == rbase + 1 ? ay1 : 0.f);
    unsigned short* gw = geow + i * 4;
    gw[0] = f2bf(gy0 * gx0);
    gw[1] = f2bf(gy0 * gx1);
    gw[2] = f2bf(gy1 * gx0);
    gw[3] = f2bf(gy1 * gx1);
    geoi[i] = (unsigned short)((rbase << 7) + cbase);
  }
  __syncthreads();

  // ===== phase 3: deform MFMA (R16 structure) + setprio around MFMA cluster =====
  int l4 = ln;
  int s4 = lane >> 4;        // k-slice 0..3
  int tapS = lane >> 5;      // which tap of the pair
  int chalf = s4 & 1;        // which 8ch half of the 16ch chunk

  f32x4 acc[2][4];  // [m-tile (px 16)][n-tile (oc 16)]
#pragma unroll
  for (int m = 0; m < 2; ++m)
#pragma unroll
    for (int n = 0; n < 4; ++n) acc[m][n] = (f32x4){0.f, 0.f, 0.f, 0.f};

  for (int tp = 0; tp < 5; ++tp) {
    int tap = tp * 2 + tapS;
    bool live = (tap < 9);
    float w00[2], w01[2], w10[2], w11[2];
    const unsigned short* cpb[2];
#pragma unroll
    for (int m = 0; m < 2; ++m) {
      if (live) {
        int px = (wv << 5) + (m << 4) + l4;
        int gidx = (tap << 7) + px;
        u16x4 wq = *(const u16x4*)(geow + gidx * 4);
        unsigned ib = geoi[gidx];
        w00[m] = bf2f(wq[0]);
        w01[m] = bf2f(wq[1]);
        w10[m] = bf2f(wq[2]);
        w11[m] = bf2f(wq[3]);
        cpb[m] = xtb + (size_t)ib * 64 + (chalf << 3);
      } else {
        cpb[m] = xtb;
        w00[m] = w01[m] = w10[m] = w11[m] = 0.f;
      }
    }
#pragma unroll 2
    for (int chunk = 0; chunk < 4; ++chunk) {
      int it = chunk * 5 + tp;
      s16x8 A[2];
#pragma unroll
      for (int m = 0; m < 2; ++m) {
        if (live) {
          const unsigned short* cp = cpb[m] + (chunk << 4);
          s16x8 c00 = *(const s16x8*)(cp);
          s16x8 c01 = *(const s16x8*)(cp + 64);
          s16x8 c10 = *(const s16x8*)(cp + 8192);
          s16x8 c11 = *(const s16x8*)(cp + 8192 + 64);
          u32x4 au;
#pragma unroll
          for (int jj = 0; jj < 4; ++jj) {
            float v0 = w00[m] * bf2f((unsigned short)c00[2 * jj]) +
                       w01[m] * bf2f((unsigned short)c01[2 * jj]) +
                       w10[m] * bf2f((unsigned short)c10[2 * jj]) +
                       w11[m] * bf2f((unsigned short)c11[2 * jj]);
            float v1 = w00[m] * bf2f((unsigned short)c00[2 * jj + 1]) +
                       w01[m] * bf2f((unsigned short)c01[2 * jj + 1]) +
                       w10[m] * bf2f((unsigned short)c10[2 * jj + 1]) +
                       w11[m] * bf2f((unsigned short)c11[2 * jj + 1]);
            au[jj] = cvt_pk_bf16(v0, v1);
          }
          A[m] = __builtin_bit_cast(s16x8, au);
        } else {
          A[m] = (s16x8){0, 0, 0, 0, 0, 0, 0, 0};
        }
      }
      const unsigned short* wb = wbtB + (((size_t)it) << 11) + (lane << 3);
      __builtin_amdgcn_s_setprio(1);
#pragma unroll
      for (int n = 0; n < 4; ++n) {
        s16x8 Bf = *(const s16x8*)(wb + (n << 9));
        acc[0][n] = __builtin_amdgcn_mfma_f32_16x16x32_bf16(A[0], Bf, acc[0][n], 0, 0, 0);
        acc[1][n] = __builtin_amdgcn_mfma_f32_16x16x32_bf16(A[1], Bf, acc[1][n], 0, 0, 0);
      }
      __builtin_amdgcn_s_setprio(0);
    }
  }

  // ===== epilogue: bias + store + per-channel stats (8-way replicated atomics) =====
  float sac[4], ssc[4];
#pragma unroll
  for (int n = 0; n < 4; ++n) { sac[n] = 0.f; ssc[n] = 0.f; }
#pragma unroll
  for (int m = 0; m < 2; ++m) {
    int px0 = (wv << 5) + (m << 4) + (s4 << 2);
#pragma unroll
    for (int n = 0; n < 4; ++n) {
      int oc = (n << 4) + l4;
      float bv = bias[oc];
      float4 o;
      o.x = acc[m][n][0] + bv;
      o.y = acc[m][n][1] + bv;
      o.z = acc[m][n][2] + bv;
      o.w = acc[m][n][3] + bv;
      sac[n] += o.x + o.y + o.z + o.w;
      ssc[n] += o.x * o.x + o.y * o.y + o.z * o.z + o.w * o.w;
      *(float4*)(y + (((size_t)(b << 6) + oc) << 14) + hw + px0) = o;
    }
  }
  // reduce over the 4 k-slice lanes (same l4, different s4): xor 16, 32
#pragma unroll
  for (int n = 0; n < 4; ++n) {
    sac[n] += __shfl_xor(sac[n], 16);
    sac[n] += __shfl_xor(sac[n], 32);
    ssc[n] += __shfl_xor(ssc[n], 16);
    ssc[n] += __shfl_xor(ssc[n], 32);
  }
  if (lane < 16) {
#pragma unroll
    for (int n = 0; n < 4; ++n) {
      int oc = (n << 4) + lane;
      offm[(wv << 6) + oc] = sac[n];
      offm[256 + (wv << 6) + oc] = ssc[n];
    }
  }
  __syncthreads();
  if (t < 64) {
    float S = offm[t] + offm[64 + t] + offm[128 + t] + offm[192 + t];
    float SS = offm[256 + t] + offm[320 + t] + offm[384 + t] + offm[448 + t];
    float* sb = stat + ((bx & 7) << 7);   // replica slot: contention 1024 -> 128 per address
    atomicAdd(sb + t, S);
    atomicAdd(sb + 64 + t, SS);
  }
}

// ---------------- kernel D: batchnorm scale/shift + relu, in place ----------------
__global__ __launch_bounds__(256) void bnrelu_kernel(
    float* __restrict__ y, const float* __restrict__ stat,
    const float* __restrict__ gamma, const float* __restrict__ beta) {
  __shared__ float gs[64], bs[64];
  int t = threadIdx.x;
  if (t < 64) {
    float S = 0.f, SS = 0.f;
#pragma unroll
    for (int k = 0; k < 8; ++k) {
      S += stat[(k << 7) + t];
      SS += stat[(k << 7) + 64 + t];
    }
    float mean = S * (1.f / (float)NPIX);
    float var = SS * (1.f / (float)NPIX) - mean * mean;
    float r = rsqrtf(var + EPSv);
    float g = gamma[t] * r;
    gs[t] = g;
    bs[t] = beta[t] - mean * g;
  }
  __syncthreads();
  float4* y4 = (float4*)y;
  for (int i = blockIdx.x * 256 + t; i < 2097152; i += gridDim.x * 256) {
    int c = (i >> 12) & 63;
    float g = gs[c];
    float bt = bs[c];
    float4 v = y4[i];
    v.x = fmaxf(v.x * g + bt, 0.f);
    v.y = fmaxf(v.y * g + bt, 0.f);
    v.z = fmaxf(v.z * g + bt, 0.f);
    v.w = fmaxf(v.w * g + bt, 0.f);
    y4[i] = v;
  }
}

extern "C" void kernel_launch(void* const* d_in, const int* in_sizes, int n_in,
                              void* d_out, int out_size, void* d_ws, size_t ws_size,
                              hipStream_t stream) {
  const float* x     = (const float*)d_in[0];
  const float* off_w = (const float*)d_in[1];
  const float* off_b = (const float*)d_in[2];
  const float* mod_w = (const float*)d_in[3];
  const float* mod_b = (const float*)d_in[4];
  const float* w     = (const float*)d_in[5];
  const float* b     = (const float*)d_in[6];
  const float* gamma = (const float*)d_in[7];
  const float* beta  = (const float*)d_in[8];
  float* out = (float*)d_out;
  float* ws  = (float*)d_ws;

  unsigned short* xt  = (unsigned short*)(ws + XT_OFF);
  unsigned short* wbtA = (unsigned short*)(ws + WBTA_OFF);
  unsigned short* wbtB = (unsigned short*)(ws + WBTB_OFF);
  float* stat  = ws + STAT_OFF;

  prep_xform_kernel<<<752, 256, 0, stream>>>(x, xt, off_w, mod_w, w, wbtA, wbtB, stat);
  fused_dconv_kernel<<<1024, 256, 0, stream>>>(xt, wbtA, wbtB, off_b, mod_b, b, out, stat);
  bnrelu_kernel<<<2048, 256, 0, stream>>>(out, stat, gamma, beta);
}

// Round 13
// 201.424 us; speedup vs baseline: 1.2257x; 1.0688x over previous
//
#include <hip/hip_runtime.h>
#include <math.h>

// Problem constants: B=8, C=64 (in), OC=64 (out), H=W=128, K=3x3=9, PAD=1.
#define Hn 128
#define Wn 128
#define HW 16384
#define NPIX 131072
#define EPSv 1e-5f

// ws layout (floats)
#define XT_OFF   0            // x_t bf16 channels-last [b][y][x][c]: 8388608 shorts = 4194304 floats
#define WBTA_OFF 4194304      // 20480 shorts = 10240 floats
#define WBTB_OFF 4204544      // 40960 shorts = 20480 floats
#define STAT_OFF 4225024      // 8 replicas x 128 (sum[64], sumsq[64]) = 1024 floats

// R23 (this round): phase-1 LDS staging. Overhead accounting across R16/R19/
// R22 shows a FIXED ~83us harness floor (not per-dispatch) -> only real
// lever left is fused (112.3us = ~30us phase-1 + ~82us phase-3; phase-3
// resisted 5 attacks). Phase 1's rows are statically h-1,h,h+1 -> canonical
// fix: per 16-ch chunk, cooperatively stream 3 rows x 128 px x 16 ch (12KB,
// coalesced, OOB rows zero-filled) into LDS, then B-fragments come from
// ds_read_b128 (4-way conflict = 1.58x, cheap) instead of 128B-strided
// quarter-consumed global lines. LDS 37.6KB < 40KB keeps 4 blocks/CU.
// Phases 2/3/epilogue byte-identical to R22 (passed, 215.3us).

typedef short s16x8 __attribute__((ext_vector_type(8)));
typedef unsigned short u16x4 __attribute__((ext_vector_type(4)));
typedef float f32x4 __attribute__((ext_vector_type(4)));
typedef unsigned int u32x4 __attribute__((ext_vector_type(4)));

__device__ __forceinline__ unsigned short f2bf(float f) {
  unsigned u = __float_as_uint(f);
  return (unsigned short)((u + 0x7fffu + ((u >> 16) & 1u)) >> 16);  // RNE
}
__device__ __forceinline__ float bf2f(unsigned short s) {
  return __uint_as_float((unsigned)s << 16);
}
__device__ __forceinline__ unsigned cvt_pk_bf16(float lo, float hi) {
  unsigned r;
  asm("v_cvt_pk_bf16_f32 %0, %1, %2" : "=v"(r) : "v"(lo), "v"(hi));
  return r;
}

// ---------------- merged prep(+stat zero) + xform kernel ----------------
// blocks 0..511: xform x (NCHW fp32) -> x_t (NHWC bf16). blocks 512..751: weight pack.
__global__ __launch_bounds__(256) void prep_xform_kernel(
    const float* __restrict__ x, unsigned short* __restrict__ xt,
    const float* __restrict__ off_w, const float* __restrict__ mod_w,
    const float* __restrict__ w, unsigned short* __restrict__ wbtA,
    unsigned short* __restrict__ wbtB, float* __restrict__ stat) {
  int blk = blockIdx.x;
  if (blk < 512) {
    int b = blk & 7;
    int hw = ((blk >> 3) << 8) + threadIdx.x;   // 0..16383
    const float* xb = x + ((size_t)(b << 6) << 14) + hw;
    unsigned short* o = xt + (((size_t)(b << 14)) + hw) * 64;
#pragma unroll
    for (int g = 0; g < 8; ++g) {
      float v[8];
#pragma unroll
      for (int j = 0; j < 8; ++j) v[j] = xb[(size_t)((g << 3) + j) << 14];
      s16x8 pk;
#pragma unroll
      for (int j = 0; j < 8; ++j) pk[j] = (short)f2bf(v[j]);
      *(s16x8*)(o + (g << 3)) = pk;
    }
    return;
  }
  int i = ((blk - 512) << 8) + threadIdx.x;
  if (i < 1024) stat[i] = 0.f;   // 8 replica slots
  if (i < 20480) {
    // wbtA: A-operand (weights as rows) for phase 1 of the fused kernel.
    int e = i & 31, oc = (i >> 5) & 31, it = i >> 10;
    int tp = it % 5, chunk = it / 5;
    int tap = tp * 2 + (e >> 4);
    int c = (chunk << 4) + (e & 15);
    float v = 0.f;
    if (tap < 9) {
      if (oc < 18) v = off_w[(oc * 64 + c) * 9 + tap];
      else if (oc < 27) v = mod_w[((oc - 18) * 64 + c) * 9 + tap];
    }
    wbtA[i] = f2bf(v);
  } else if (i < 20480 + 40960) {
    // wbtB: B-operand fragments for phase 3 (deform).
    // index = ((it*4 + nt)*64 + lane)*8 + j
    // value = w[oc = nt*16 + (lane&15)][c][tap], where
    //   tap = (it%5)*2 + (lane>>5), c = (it/5)*16 + ((lane>>4)&1)*8 + j
    int j = i - 20480;
    int j3 = j & 7;
    int l = (j >> 3) & 63;
    int nt = (j >> 9) & 3;
    int it = j >> 11;
    int tp = it % 5, chunk = it / 5;
    int tap = tp * 2 + (l >> 5);
    int c = (chunk << 4) + (((l >> 4) & 1) << 3) + j3;
    int oc = (nt << 4) + (l & 15);
    float v = (tap < 9) ? w[(oc * 64 + c) * 9 + tap] : 0.f;
    wbtB[j] = f2bf(v);
  }
}

// ---------------- fused kernel: convA (LDS-staged ->LDS) + geometry + deform MFMA + stats ----------------
__global__ __launch_bounds__(256, 4) void fused_dconv_kernel(
    const unsigned short* __restrict__ xt, const unsigned short* __restrict__ wbtA,
    const unsigned short* __restrict__ wbtB,
    const float* __restrict__ off_b, const float* __restrict__ mod_b,
    const float* __restrict__ bias, float* __restrict__ y,
    float* __restrict__ stat) {
  __shared__ float offm[27 * 128];              // 13824 B; reused for stats reduce at the end
  __shared__ unsigned short geow[9 * 128 * 4];  // 9216 B: w00,w01,w10,w11 bf16 (mask folded)
  __shared__ unsigned short geoi[9 * 128];      // 2304 B: ibase = rbase*128+cbase
  __shared__ unsigned short stage[3 * 128 * 16];// 12288 B: phase-1 row cache [row][px][16ch]
  int t = threadIdx.x;
  int bx = blockIdx.x;                  // 1024 = 8 b x 128 h
  int b = bx & 7, h = bx >> 3;
  int lane = t & 63, wv = t >> 6;
  int ln = lane & 15, quad = (lane >> 4) & 3;
  int hw = h << 7;

  const unsigned short* xtb = xt + ((size_t)(b << 14)) * 64;

  // ===== phase 1: offset+mask conv via MFMA (B-fragments from staged LDS rows) =====
  {
    int p0 = (wv << 5) + ln, p1 = p0 + 16;
    int s_ = quad >> 1, cj = (quad & 1) << 3;
    f32x4 acc1[2][2];
#pragma unroll
    for (int mt = 0; mt < 2; ++mt)
#pragma unroll
      for (int nt = 0; nt < 2; ++nt) acc1[mt][nt] = (f32x4){0.f, 0.f, 0.f, 0.f};

    for (int chunk = 0; chunk < 4; ++chunk) {
      // cooperative stage: rows h-1,h,h+1 x 128 px x 16 ch of this chunk (OOB rows = 0)
      for (int q = t; q < 768; q += 256) {
        int row = q >> 8;          // 0..2
        int rem = q & 255;
        int px = rem >> 1;
        int half = rem & 1;
        int gy = h - 1 + row;
        s16x8 v = (s16x8){0, 0, 0, 0, 0, 0, 0, 0};
        if (gy >= 0 && gy < Hn)
          v = *(const s16x8*)(xtb + ((size_t)(gy << 7)) * 64 + (px << 6) + (chunk << 4) + (half << 3));
        *(s16x8*)(stage + (q << 3)) = v;
      }
      __syncthreads();

#pragma unroll
      for (int tp = 0; tp < 5; ++tp) {
        int it = chunk * 5 + tp;
        int tap = tp * 2 + s_;
        s16x8 B0 = (s16x8){0, 0, 0, 0, 0, 0, 0, 0};
        s16x8 B1 = (s16x8){0, 0, 0, 0, 0, 0, 0, 0};
        if (tap < 9) {
          const unsigned short* rowl = stage + (tap / 3) * 2048 + cj;  // shorts
          int gx0 = p0 + tap % 3 - 1;
          int gx1 = p1 + tap % 3 - 1;
          if (gx0 >= 0 && gx0 < Wn) B0 = *(const s16x8*)(rowl + (gx0 << 4));
          if (gx1 >= 0 && gx1 < Wn) B1 = *(const s16x8*)(rowl + (gx1 << 4));
        }
#pragma unroll
        for (int mt = 0; mt < 2; ++mt) {
          s16x8 A = *(const s16x8*)(wbtA + (size_t)((it << 5) + (mt << 4) + ln) * 32 + (quad << 3));
          acc1[mt][0] = __builtin_amdgcn_mfma_f32_16x16x32_bf16(A, B0, acc1[mt][0], 0, 0, 0);
          acc1[mt][1] = __builtin_amdgcn_mfma_f32_16x16x32_bf16(A, B1, acc1[mt][1], 0, 0, 0);
        }
      }
      __syncthreads();   // protect stage before next chunk overwrites
    }

#pragma unroll
    for (int mt = 0; mt < 2; ++mt)
#pragma unroll
      for (int r = 0; r < 4; ++r) {
        int oc = (mt << 4) + (quad << 2) + r;
#pragma unroll
        for (int nt = 0; nt < 2; ++nt) {
          int px = (wv << 5) + (nt << 4) + ln;
          float val = acc1[mt][nt][r];
          if (oc < 18) {
            offm[(oc << 7) + px] = val + off_b[oc];
          } else if (oc < 27) {
            float z = val + mod_b[oc - 18];
            offm[(oc << 7) + px] = 2.f / (1.f + expf(-z));
          }
        }
      }
  }
  __syncthreads();

  // ===== phase 2: geometry for 128 px x 9 taps from LDS =====
  for (int i = t; i < 1152; i += 256) {
    int tap = i >> 7, p2 = i & 127;
    float dy = offm[((2 * tap) << 7) + p2];
    float dx = offm[((2 * tap + 1) << 7) + p2];
    float m = offm[((18 + tap) << 7) + p2];
    float py = dy + (float)(h + tap / 3 - 1);
    float pxf = dx + (float)(p2 + tap % 3 - 1);
    float y0f = floorf(py), x0f = floorf(pxf);
    float ly = py - y0f, lx = pxf - x0f;
    int y0 = (int)y0f, x0 = (int)x0f;
    int y1 = y0 + 1, x1 = x0 + 1;
    float fy0 = (y0 >= 0 && y0 < Hn) ? 1.f : 0.f;
    float fy1 = (y1 >= 0 && y1 < Hn) ? 1.f : 0.f;
    float fx0 = (x0 >= 0 && x0 < Wn) ? 1.f : 0.f;
    float fx1 = (x1 >= 0 && x1 < Wn) ? 1.f : 0.f;
    float ax0 = (1.f - lx) * fx0, ax1 = lx * fx1;
    float ay0 = (1.f - ly) * fy0 * m, ay1 = ly * fy1 * m;
    int cy0 = min(max(y0, 0), Hn - 1), cy1 = min(max(y1, 0), Hn - 1);
    int cx0 = min(max(x0, 0), Wn - 1), cx1 = min(max(x1, 0), Wn - 1);
    int cbase = min(cx0, Wn - 2), rbase = min(cy0, Hn - 2);
    float gx0 = (cx0 == cbase ? ax0 : 0.f) + (cx1 == cbase ? ax1 : 0.f);
    float gx1 = (cx0 == cbase + 1 ? ax0 : 0.f) + (cx1 == cbase + 1 ? ax1 : 0.f);
    float gy0 = (cy0 == rbase ? ay0 : 0.f) + (cy1 == rbase ? ay1 : 0.f);
    float gy1 = (cy0 == rbase + 1 ? ay0 : 0.f) + (cy1 == rbase + 1 ? ay1 : 0.f);
    unsigned short* gw = geow + i * 4;
    gw[0] = f2bf(gy0 * gx0);
    gw[1] = f2bf(gy0 * gx1);
    gw[2] = f2bf(gy1 * gx0);
    gw[3] = f2bf(gy1 * gx1);
    geoi[i] = (unsigned short)((rbase << 7) + cbase);
  }
  __syncthreads();

  // ===== phase 3: deform MFMA (R16 structure) + setprio around MFMA cluster =====
  int l4 = ln;
  int s4 = lane >> 4;        // k-slice 0..3
  int tapS = lane >> 5;      // which tap of the pair
  int chalf = s4 & 1;        // which 8ch half of the 16ch chunk

  f32x4 acc[2][4];  // [m-tile (px 16)][n-tile (oc 16)]
#pragma unroll
  for (int m = 0; m < 2; ++m)
#pragma unroll
    for (int n = 0; n < 4; ++n) acc[m][n] = (f32x4){0.f, 0.f, 0.f, 0.f};

  for (int tp = 0; tp < 5; ++tp) {
    int tap = tp * 2 + tapS;
    bool live = (tap < 9);
    float w00[2], w01[2], w10[2], w11[2];
    const unsigned short* cpb[2];
#pragma unroll
    for (int m = 0; m < 2; ++m) {
      if (live) {
        int px = (wv << 5) + (m << 4) + l4;
        int gidx = (tap << 7) + px;
        u16x4 wq = *(const u16x4*)(geow + gidx * 4);
        unsigned ib = geoi[gidx];
        w00[m] = bf2f(wq[0]);
        w01[m] = bf2f(wq[1]);
        w10[m] = bf2f(wq[2]);
        w11[m] = bf2f(wq[3]);
        cpb[m] = xtb + (size_t)ib * 64 + (chalf << 3);
      } else {
        cpb[m] = xtb;
        w00[m] = w01[m] = w10[m] = w11[m] = 0.f;
      }
    }
#pragma unroll 2
    for (int chunk = 0; chunk < 4; ++chunk) {
      int it = chunk * 5 + tp;
      s16x8 A[2];
#pragma unroll
      for (int m = 0; m < 2; ++m) {
        if (live) {
          const unsigned short* cp = cpb[m] + (chunk << 4);
          s16x8 c00 = *(const s16x8*)(cp);
          s16x8 c01 = *(const s16x8*)(cp + 64);
          s16x8 c10 = *(const s16x8*)(cp + 8192);
          s16x8 c11 = *(const s16x8*)(cp + 8192 + 64);
          u32x4 au;
#pragma unroll
          for (int jj = 0; jj < 4; ++jj) {
            float v0 = w00[m] * bf2f((unsigned short)c00[2 * jj]) +
                       w01[m] * bf2f((unsigned short)c01[2 * jj]) +
                       w10[m] * bf2f((unsigned short)c10[2 * jj]) +
                       w11[m] * bf2f((unsigned short)c11[2 * jj]);
            float v1 = w00[m] * bf2f((unsigned short)c00[2 * jj + 1]) +
                       w01[m] * bf2f((unsigned short)c01[2 * jj + 1]) +
                       w10[m] * bf2f((unsigned short)c10[2 * jj + 1]) +
                       w11[m] * bf2f((unsigned short)c11[2 * jj + 1]);
            au[jj] = cvt_pk_bf16(v0, v1);
          }
          A[m] = __builtin_bit_cast(s16x8, au);
        } else {
          A[m] = (s16x8){0, 0, 0, 0, 0, 0, 0, 0};
        }
      }
      const unsigned short* wb = wbtB + (((size_t)it) << 11) + (lane << 3);
      __builtin_amdgcn_s_setprio(1);
#pragma unroll
      for (int n = 0; n < 4; ++n) {
        s16x8 Bf = *(const s16x8*)(wb + (n << 9));
        acc[0][n] = __builtin_amdgcn_mfma_f32_16x16x32_bf16(A[0], Bf, acc[0][n], 0, 0, 0);
        acc[1][n] = __builtin_amdgcn_mfma_f32_16x16x32_bf16(A[1], Bf, acc[1][n], 0, 0, 0);
      }
      __builtin_amdgcn_s_setprio(0);
    }
  }

  // ===== epilogue: bias + store + per-channel stats (8-way replicated atomics) =====
  float sac[4], ssc[4];
#pragma unroll
  for (int n = 0; n < 4; ++n) { sac[n] = 0.f; ssc[n] = 0.f; }
#pragma unroll
  for (int m = 0; m < 2; ++m) {
    int px0 = (wv << 5) + (m << 4) + (s4 << 2);
#pragma unroll
    for (int n = 0; n < 4; ++n) {
      int oc = (n << 4) + l4;
      float bv = bias[oc];
      float4 o;
      o.x = acc[m][n][0] + bv;
      o.y = acc[m][n][1] + bv;
      o.z = acc[m][n][2] + bv;
      o.w = acc[m][n][3] + bv;
      sac[n] += o.x + o.y + o.z + o.w;
      ssc[n] += o.x * o.x + o.y * o.y + o.z * o.z + o.w * o.w;
      *(float4*)(y + (((size_t)(b << 6) + oc) << 14) + hw + px0) = o;
    }
  }
  // reduce over the 4 k-slice lanes (same l4, different s4): xor 16, 32
#pragma unroll
  for (int n = 0; n < 4; ++n) {
    sac[n] += __shfl_xor(sac[n], 16);
    sac[n] += __shfl_xor(sac[n], 32);
    ssc[n] += __shfl_xor(ssc[n], 16);
    ssc[n] += __shfl_xor(ssc[n], 32);
  }
  if (lane < 16) {
#pragma unroll
    for (int n = 0; n < 4; ++n) {
      int oc = (n << 4) + lane;
      offm[(wv << 6) + oc] = sac[n];
      offm[256 + (wv << 6) + oc] = ssc[n];
    }
  }
  __syncthreads();
  if (t < 64) {
    float S = offm[t] + offm[64 + t] + offm[128 + t] + offm[192 + t];
    float SS = offm[256 + t] + offm[320 + t] + offm[384 + t] + offm[448 + t];
    float* sb = stat + ((bx & 7) << 7);   // replica slot: contention 1024 -> 128 per address
    atomicAdd(sb + t, S);
    atomicAdd(sb + 64 + t, SS);
  }
}

// ---------------- kernel D: batchnorm scale/shift + relu, in place ----------------
__global__ __launch_bounds__(256) void bnrelu_kernel(
    float* __restrict__ y, const float* __restrict__ stat,
    const float* __restrict__ gamma, const float* __restrict__ beta) {
  __shared__ float gs[64], bs[64];
  int t = threadIdx.x;
  if (t < 64) {
    float S = 0.f, SS = 0.f;
#pragma unroll
    for (int k = 0; k < 8; ++k) {
      S += stat[(k << 7) + t];
      SS += stat[(k << 7) + 64 + t];
    }
    float mean = S * (1.f / (float)NPIX);
    float var = SS * (1.f / (float)NPIX) - mean * mean;
    float r = rsqrtf(var + EPSv);
    float g = gamma[t] * r;
    gs[t] = g;
    bs[t] = beta[t] - mean * g;
  }
  __syncthreads();
  float4* y4 = (float4*)y;
  for (int i = blockIdx.x * 256 + t; i < 2097152; i += gridDim.x * 256) {
    int c = (i >> 12) & 63;
    float g = gs[c];
    float bt = bs[c];
    float4 v = y4[i];
    v.x = fmaxf(v.x * g + bt, 0.f);
    v.y = fmaxf(v.y * g + bt, 0.f);
    v.z = fmaxf(v.z * g + bt, 0.f);
    v.w = fmaxf(v.w * g + bt, 0.f);
    y4[i] = v;
  }
}

extern "C" void kernel_launch(void* const* d_in, const int* in_sizes, int n_in,
                              void* d_out, int out_size, void* d_ws, size_t ws_size,
                              hipStream_t stream) {
  const float* x     = (const float*)d_in[0];
  const float* off_w = (const float*)d_in[1];
  const float* off_b = (const float*)d_in[2];
  const float* mod_w = (const float*)d_in[3];
  const float* mod_b = (const float*)d_in[4];
  const float* w     = (const float*)d_in[5];
  const float* b     = (const float*)d_in[6];
  const float* gamma = (const float*)d_in[7];
  const float* beta  = (const float*)d_in[8];
  float* out = (float*)d_out;
  float* ws  = (float*)d_ws;

  unsigned short* xt  = (unsigned short*)(ws + XT_OFF);
  unsigned short* wbtA = (unsigned short*)(ws + WBTA_OFF);
  unsigned short* wbtB = (unsigned short*)(ws + WBTB_OFF);
  float* stat  = ws + STAT_OFF;

  prep_xform_kernel<<<752, 256, 0, stream>>>(x, xt, off_w, mod_w, w, wbtA, wbtB, stat);
  fused_dconv_kernel<<<1024, 256, 0, stream>>>(xt, wbtA, wbtB, off_b, mod_b, b, out, stat);
  bnrelu_kernel<<<2048, 256, 0, stream>>>(out, stat, gamma, beta);
}